// Round 1
// baseline (334.524 us; speedup 1.0000x reference)
//
#include <hip/hip_runtime.h>
#include <hip/hip_bf16.h>

// Problem constants: B=4 S=8192 D=1024 K=1024, TAU=1.0
constexpr int MM   = 32768;   // B*S
constexpr int NN   = 1024;    // output cols of both GEMMs (K for gemm1, D for gemm2)
constexpr int KRED = 1024;    // reduction dim of both GEMMs
constexpr int LDAB = KRED * 2; // bytes per row of bf16 A / Bt

using s16x8 = __attribute__((ext_vector_type(8))) short;
using f32x4 = __attribute__((ext_vector_type(4))) float;

__device__ __forceinline__ unsigned short f2bf(float f) {
  unsigned u = __float_as_uint(f);
  return (unsigned short)((u + 0x7fffu + ((u >> 16) & 1u)) >> 16);
}

__device__ __forceinline__ void gload_lds16(const void* g, void* l) {
  __builtin_amdgcn_global_load_lds(
      (const __attribute__((address_space(1))) void*)g,
      (__attribute__((address_space(3))) void*)l, 16, 0, 0);
}

__device__ __forceinline__ float wave_sum(float v) {
#pragma unroll
  for (int o = 32; o > 0; o >>= 1) v += __shfl_xor(v, o);
  return v;
}
__device__ __forceinline__ float wave_max(float v) {
#pragma unroll
  for (int o = 32; o > 0; o >>= 1) v = fmaxf(v, __shfl_xor(v, o));
  return v;
}

// ---------------------------------------------------------------------------
// prep_cb: one block per codebook row k. Produces CB (bf16 [K,D]),
// CT (bf16 [D,K] = codebook^T), c2[k] = sum_d C[k,d]^2 (f32, exact).
// ---------------------------------------------------------------------------
__global__ __launch_bounds__(256) void prep_cb(const float* __restrict__ C,
                                               unsigned short* __restrict__ CB,
                                               unsigned short* __restrict__ CT,
                                               float* __restrict__ c2) {
  int k = blockIdx.x;   // 0..1023
  int t = threadIdx.x;  // 0..255, 4 elements each
  const float4 v = *(const float4*)(C + (size_t)k * 1024 + t * 4);
  ushort4 b = make_ushort4(f2bf(v.x), f2bf(v.y), f2bf(v.z), f2bf(v.w));
  *(ushort4*)(CB + (size_t)k * 1024 + t * 4) = b;
  CT[(size_t)(t * 4 + 0) * 1024 + k] = b.x;
  CT[(size_t)(t * 4 + 1) * 1024 + k] = b.y;
  CT[(size_t)(t * 4 + 2) * 1024 + k] = b.z;
  CT[(size_t)(t * 4 + 3) * 1024 + k] = b.w;
  float p = v.x * v.x + v.y * v.y + v.z * v.z + v.w * v.w;
  p = wave_sum(p);
  __shared__ float red[4];
  if ((t & 63) == 0) red[t >> 6] = p;
  __syncthreads();
  if (t == 0) c2[k] = red[0] + red[1] + red[2] + red[3];
}

// ---------------------------------------------------------------------------
// prep_x: one block per embedding row m. Produces Xb (bf16 [M,D]) and
// x2[m] = sum_d X[m,d]^2 (f32, from the ORIGINAL f32 data).
// ---------------------------------------------------------------------------
__global__ __launch_bounds__(256) void prep_x(const float* __restrict__ X,
                                              unsigned short* __restrict__ Xb,
                                              float* __restrict__ x2) {
  int m = blockIdx.x;
  int t = threadIdx.x;
  const float4 v = *(const float4*)(X + (size_t)m * 1024 + t * 4);
  ushort4 b = make_ushort4(f2bf(v.x), f2bf(v.y), f2bf(v.z), f2bf(v.w));
  *(ushort4*)(Xb + (size_t)m * 1024 + t * 4) = b;
  float p = v.x * v.x + v.y * v.y + v.z * v.z + v.w * v.w;
  p = wave_sum(p);
  __shared__ float red[4];
  if ((t & 63) == 0) red[t >> 6] = p;
  __syncthreads();
  if (t == 0) x2[m] = red[0] + red[1] + red[2] + red[3];
}

// ---------------------------------------------------------------------------
// gemm_bt<MODE>: out[M,N] = A[M,K] @ Bt[N,K]^T  (bf16 in, f32 out)
// MODE==1: epilogue v -> -sqrt(max(x2[row] + c2[col] - 2v, 0))  (logits)
// MODE==0: plain store.
// 128x128 tile, BK=64, 4 waves (2x2), mfma_f32_16x16x32_bf16,
// global_load_lds width-16 staging (m97 structure).
// ---------------------------------------------------------------------------
template <int MODE>
__global__ __launch_bounds__(256) void gemm_bt(const unsigned short* __restrict__ A,
                                               const unsigned short* __restrict__ Bt,
                                               float* __restrict__ out,
                                               const float* __restrict__ x2,
                                               const float* __restrict__ c2) {
  __shared__ __align__(16) short As[128 * 64];
  __shared__ __align__(16) short Bs[128 * 64];

  int bid = blockIdx.x;                  // 2048 blocks
  int swz = (bid & 7) * 256 + (bid >> 3);  // XCD-aware swizzle (2048 % 8 == 0)
  int bm = swz >> 3;                     // 0..255
  int bn = swz & 7;                      // 0..7
  int brow0 = bm * 128, bcol0 = bn * 128;

  int tid = threadIdx.x;
  int l = tid & 63, w = tid >> 6;        // lane, wave(0..3)
  int wr = w >> 1, wc = w & 1;           // 2x2 wave grid, each 64x64 out
  int lr = l & 15, lh = l >> 4;          // fragment row / k-group

  const char* Abase = (const char*)A + (size_t)brow0 * LDAB;
  const char* Bbase = (const char*)Bt + (size_t)bcol0 * LDAB;
  int srcRow = l >> 3;                   // 0..7 row within 8-row segment
  int srcOff = (l & 7) * 16;             // byte offset within 128B row

  f32x4 acc[4][4] = {};

  for (int kt = 0; kt < KRED / 64; ++kt) {
    int kb = kt * 128;  // byte offset along k (64 bf16)
#pragma unroll
    for (int i = 0; i < 4; ++i) {
      int seg = w * 4 + i;               // 0..15 -> 8 rows each
      int row = seg * 8 + srcRow;
      gload_lds16(Abase + (size_t)row * LDAB + kb + srcOff, (short*)As + seg * 512);
      gload_lds16(Bbase + (size_t)row * LDAB + kb + srcOff, (short*)Bs + seg * 512);
    }
    __syncthreads();
#pragma unroll
    for (int t = 0; t < 2; ++t) {        // BK=64 = 2 k-steps of 32
      s16x8 af[4], bf[4];
#pragma unroll
      for (int i = 0; i < 4; ++i)
        af[i] = *(const s16x8*)&As[(wr * 64 + i * 16 + lr) * 64 + t * 32 + lh * 8];
#pragma unroll
      for (int j = 0; j < 4; ++j)
        bf[j] = *(const s16x8*)&Bs[(wc * 64 + j * 16 + lr) * 64 + t * 32 + lh * 8];
#pragma unroll
      for (int i = 0; i < 4; ++i)
#pragma unroll
        for (int j = 0; j < 4; ++j)
          acc[i][j] = __builtin_amdgcn_mfma_f32_16x16x32_bf16(af[i], bf[j], acc[i][j], 0, 0, 0);
    }
    __syncthreads();
  }

  // Epilogue. C/D layout: col = lane&15, row = (lane>>4)*4 + reg.
#pragma unroll
  for (int i = 0; i < 4; ++i) {
    int row0 = brow0 + wr * 64 + i * 16 + lh * 4;
#pragma unroll
    for (int r = 0; r < 4; ++r) {
      int row = row0 + r;
      float xv = (MODE == 1) ? x2[row] : 0.0f;
#pragma unroll
      for (int j = 0; j < 4; ++j) {
        int col = bcol0 + wc * 64 + j * 16 + lr;
        float v = acc[i][j][r];
        if (MODE == 1) {
          float d2 = xv + c2[col] - 2.0f * v;
          v = -sqrtf(fmaxf(d2, 0.0f));
        }
        out[(size_t)row * NN + col] = v;
      }
    }
  }
}

// ---------------------------------------------------------------------------
// softmax: one block per row m. w = softmax(logits + gumbel(noise)) (TAU=1),
// written as bf16 into W (reuses the X buffer).
// ---------------------------------------------------------------------------
__global__ __launch_bounds__(256) void softmax_k(const float* __restrict__ logits,
                                                 const float* __restrict__ noise,
                                                 unsigned short* __restrict__ W) {
  int m = blockIdx.x;
  int t = threadIdx.x;
  size_t base = (size_t)m * 1024 + t * 4;
  const float4 lv = *(const float4*)(logits + base);
  const float4 nv = *(const float4*)(noise + base);
  float s0 = lv.x - logf(-logf(nv.x));
  float s1 = lv.y - logf(-logf(nv.y));
  float s2 = lv.z - logf(-logf(nv.z));
  float s3 = lv.w - logf(-logf(nv.w));

  float mx = fmaxf(fmaxf(s0, s1), fmaxf(s2, s3));
  mx = wave_max(mx);
  __shared__ float redm[4];
  __shared__ float reds[4];
  if ((t & 63) == 0) redm[t >> 6] = mx;
  __syncthreads();
  mx = fmaxf(fmaxf(redm[0], redm[1]), fmaxf(redm[2], redm[3]));

  float e0 = expf(s0 - mx), e1 = expf(s1 - mx), e2 = expf(s2 - mx), e3 = expf(s3 - mx);
  float ps = e0 + e1 + e2 + e3;
  ps = wave_sum(ps);
  if ((t & 63) == 0) reds[t >> 6] = ps;
  __syncthreads();
  float inv = 1.0f / (reds[0] + reds[1] + reds[2] + reds[3]);

  *(ushort4*)(W + base) =
      make_ushort4(f2bf(e0 * inv), f2bf(e1 * inv), f2bf(e2 * inv), f2bf(e3 * inv));
}

// ---------------------------------------------------------------------------
extern "C" void kernel_launch(void* const* d_in, const int* in_sizes, int n_in,
                              void* d_out, int out_size, void* d_ws, size_t ws_size,
                              hipStream_t stream) {
  const float* emb   = (const float*)d_in[0];  // [4,8192,1024] f32
  const float* cb    = (const float*)d_in[1];  // [1024,1024]  f32
  const float* noise = (const float*)d_in[2];  // [4,8192,1024] f32

  float* quant  = (float*)d_out;               // [M, 1024] = output 0
  float* logits = (float*)d_out + (size_t)MM * NN;  // [M, 1024] = output 1

  char* ws = (char*)d_ws;
  unsigned short* XW = (unsigned short*)ws;                   // 64 MiB: X bf16, then W bf16
  unsigned short* CB = (unsigned short*)(ws + 67108864);      // 2 MiB
  unsigned short* CT = (unsigned short*)(ws + 69206016);      // 2 MiB
  float* x2 = (float*)(ws + 71303168);                        // 128 KiB
  float* c2 = (float*)(ws + 71434240);                        // 4 KiB

  prep_cb<<<dim3(1024), dim3(256), 0, stream>>>(cb, CB, CT, c2);
  prep_x<<<dim3(MM), dim3(256), 0, stream>>>(emb, XW, x2);
  gemm_bt<1><<<dim3(2048), dim3(256), 0, stream>>>(XW, CB, logits, x2, c2);
  softmax_k<<<dim3(MM), dim3(256), 0, stream>>>(logits, noise, XW);
  gemm_bt<0><<<dim3(2048), dim3(256), 0, stream>>>(XW, CT, quant, nullptr, nullptr);
}

// Round 2
// 254.363 us; speedup vs baseline: 1.3151x; 1.3151x over previous
//
#include <hip/hip_runtime.h>
#include <hip/hip_bf16.h>

// Problem constants: B=4 S=8192 D=1024 K=1024, TAU=1.0
constexpr int MM   = 32768;    // B*S
constexpr int NN   = 1024;     // output cols of both GEMMs
constexpr int KRED = 1024;     // reduction dim
constexpr int LDAB = KRED * 2; // bytes per bf16 row of A / Bt

using s16x8 = __attribute__((ext_vector_type(8))) short;
using f32x4 = __attribute__((ext_vector_type(4))) float;

__device__ __forceinline__ unsigned short f2bf(float f) {
  unsigned u = __float_as_uint(f);
  return (unsigned short)((u + 0x7fffu + ((u >> 16) & 1u)) >> 16);
}

__device__ __forceinline__ void gload_lds16(const void* g, void* l) {
  __builtin_amdgcn_global_load_lds(
      (const __attribute__((address_space(1))) void*)g,
      (__attribute__((address_space(3))) void*)l, 16, 0, 0);
}

__device__ __forceinline__ float wave_sum(float v) {
#pragma unroll
  for (int o = 32; o > 0; o >>= 1) v += __shfl_xor(v, o);
  return v;
}
__device__ __forceinline__ float wave_max(float v) {
#pragma unroll
  for (int o = 32; o > 0; o >>= 1) v = fmaxf(v, __shfl_xor(v, o));
  return v;
}

// ---------------------------------------------------------------------------
// prep_cb / prep_x / softmax (unchanged from passing round-1 kernel)
// ---------------------------------------------------------------------------
__global__ __launch_bounds__(256) void prep_cb(const float* __restrict__ C,
                                               unsigned short* __restrict__ CB,
                                               unsigned short* __restrict__ CT,
                                               float* __restrict__ c2) {
  int k = blockIdx.x;
  int t = threadIdx.x;
  const float4 v = *(const float4*)(C + (size_t)k * 1024 + t * 4);
  ushort4 b = make_ushort4(f2bf(v.x), f2bf(v.y), f2bf(v.z), f2bf(v.w));
  *(ushort4*)(CB + (size_t)k * 1024 + t * 4) = b;
  CT[(size_t)(t * 4 + 0) * 1024 + k] = b.x;
  CT[(size_t)(t * 4 + 1) * 1024 + k] = b.y;
  CT[(size_t)(t * 4 + 2) * 1024 + k] = b.z;
  CT[(size_t)(t * 4 + 3) * 1024 + k] = b.w;
  float p = v.x * v.x + v.y * v.y + v.z * v.z + v.w * v.w;
  p = wave_sum(p);
  __shared__ float red[4];
  if ((t & 63) == 0) red[t >> 6] = p;
  __syncthreads();
  if (t == 0) c2[k] = red[0] + red[1] + red[2] + red[3];
}

__global__ __launch_bounds__(256) void prep_x(const float* __restrict__ X,
                                              unsigned short* __restrict__ Xb,
                                              float* __restrict__ x2) {
  int m = blockIdx.x;
  int t = threadIdx.x;
  const float4 v = *(const float4*)(X + (size_t)m * 1024 + t * 4);
  ushort4 b = make_ushort4(f2bf(v.x), f2bf(v.y), f2bf(v.z), f2bf(v.w));
  *(ushort4*)(Xb + (size_t)m * 1024 + t * 4) = b;
  float p = v.x * v.x + v.y * v.y + v.z * v.z + v.w * v.w;
  p = wave_sum(p);
  __shared__ float red[4];
  if ((t & 63) == 0) red[t >> 6] = p;
  __syncthreads();
  if (t == 0) x2[m] = red[0] + red[1] + red[2] + red[3];
}

__global__ __launch_bounds__(256) void softmax_k(const float* __restrict__ logits,
                                                 const float* __restrict__ noise,
                                                 unsigned short* __restrict__ W) {
  int m = blockIdx.x;
  int t = threadIdx.x;
  size_t base = (size_t)m * 1024 + t * 4;
  const float4 lv = *(const float4*)(logits + base);
  const float4 nv = *(const float4*)(noise + base);
  float s0 = lv.x - logf(-logf(nv.x));
  float s1 = lv.y - logf(-logf(nv.y));
  float s2 = lv.z - logf(-logf(nv.z));
  float s3 = lv.w - logf(-logf(nv.w));

  float mx = fmaxf(fmaxf(s0, s1), fmaxf(s2, s3));
  mx = wave_max(mx);
  __shared__ float redm[4];
  __shared__ float reds[4];
  if ((t & 63) == 0) redm[t >> 6] = mx;
  __syncthreads();
  mx = fmaxf(fmaxf(redm[0], redm[1]), fmaxf(redm[2], redm[3]));

  float e0 = expf(s0 - mx), e1 = expf(s1 - mx), e2 = expf(s2 - mx), e3 = expf(s3 - mx);
  float ps = e0 + e1 + e2 + e3;
  ps = wave_sum(ps);
  if ((t & 63) == 0) reds[t >> 6] = ps;
  __syncthreads();
  float inv = 1.0f / (reds[0] + reds[1] + reds[2] + reds[3]);

  *(ushort4*)(W + base) =
      make_ushort4(f2bf(e0 * inv), f2bf(e1 * inv), f2bf(e2 * inv), f2bf(e3 * inv));
}

// ---------------------------------------------------------------------------
// gemm256<MODE>: 256x256 tile, BK=64, 8 waves, 8-phase-style schedule with
// counted vmcnt + T2 row-XOR LDS swizzle + T5 setprio.
// out[M,N] = A[M,K] @ Bt[N,K]^T (bf16 in, f32 out).
// MODE==1: epilogue v -> -sqrt(max(x2[row]+c2[col]-2v,0)).
// ---------------------------------------------------------------------------
// LDS map (128 KiB dynamic): buf p at p*65536: A tile 32KB (2 halves of
// 128rows x 128B), then B tile 32KB. Swizzle: LDS byte (r, c') holds global
// (r, c' ^ ((r&7)<<4)); reads XOR the same.
// Staging ledger (per K-tile t, parity p=t&1, 2 loads/thread per half-tile):
//   P1: stage A-h0(t+1)->buf[1-p]   (buf[1-p].A released at t-1's P3-end bar)
//   P2: stage A-h1(t+1)->buf[1-p]
//   P3: stage B-h0(t+2)->buf[p]     (buf[p].B fully read by P2-end barrier)
//   P4: stage B-h1(t+2)->buf[p]; vmcnt(4) retires exactly tile t+1's 4
//       half-tiles (12 outstanding: Bh(t+1)x2 [from t-1], Ah(t+1)x2 [P1,P2],
//       Bh(t+2)x2 [P3,P4]); last two tiles drain with vmcnt(0).
template <int MODE>
__global__ __launch_bounds__(512, 2) void gemm256(const unsigned short* __restrict__ A,
                                                  const unsigned short* __restrict__ Bt,
                                                  float* __restrict__ out,
                                                  const float* __restrict__ x2,
                                                  const float* __restrict__ c2) {
  extern __shared__ char smem[];

  int bid = blockIdx.x;                     // 512 blocks
  int swz = (bid & 7) * 64 + (bid >> 3);    // XCD swizzle (512 % 8 == 0)
  int bm = swz >> 2, bn = swz & 3;
  int brow0 = bm * 256, bcol0 = bn * 256;

  int tid = threadIdx.x;
  int l = tid & 63, w = tid >> 6;           // 8 waves
  int wm = w >> 2, wn = w & 3;              // 2x4 wave grid; per-wave 128x64
  int lr = l & 15, lh = l >> 4;
  const int xsw = (lr & 7) << 4;

  const char* AbH[2] = { (const char*)A + (size_t)brow0 * LDAB,
                         (const char*)A + (size_t)(brow0 + 128) * LDAB };
  const char* BbH[2] = { (const char*)Bt + (size_t)bcol0 * LDAB,
                         (const char*)Bt + (size_t)(bcol0 + 128) * LDAB };

  // per-thread staging geometry (2 gload_lds16 per half-tile)
  const int sr0 = tid >> 3;                 // row (j=0); j=1 adds 64
  const int sc  = (tid & 7) * 16;           // linear LDS byte col
  const int scx0 = sc ^ ((sr0 & 7) << 4);   // inverse-swizzled source col

#define STAGE(gbase, kbyte, ldsreg)                                            \
  do {                                                                         \
    gload_lds16((gbase) + (size_t)sr0 * LDAB + (kbyte) + scx0,                 \
                (ldsreg) + tid * 16);                                          \
    gload_lds16((gbase) + (size_t)(sr0 + 64) * LDAB + (kbyte) + scx0,          \
                (ldsreg) + 8192 + tid * 16);                                   \
  } while (0)

  // prologue: tile0 A+B -> buf0, tile1 B -> buf1; retire tile0 (vmcnt(4))
  STAGE(AbH[0], 0, smem + 0);
  STAGE(AbH[1], 0, smem + 16384);
  STAGE(BbH[0], 0, smem + 32768);
  STAGE(BbH[1], 0, smem + 49152);
  STAGE(BbH[0], 128, smem + 65536 + 32768);
  STAGE(BbH[1], 128, smem + 65536 + 49152);
  asm volatile("s_waitcnt vmcnt(4)" ::: "memory");
  __builtin_amdgcn_s_barrier();

  const int aoff0 = wm * 16384 + lr * 128;
  const int boff0 = (wn >> 1) * 16384 + (wn & 1) * 8192 + lr * 128;

  f32x4 acc[8][4] = {};
  s16x8 af[4][2], bf[4][2];

#pragma unroll 2
  for (int t = 0; t < 16; ++t) {
    int p = t & 1;
    char* As  = smem + p * 65536;
    char* Bs  = smem + p * 65536 + 32768;
    char* Asn = smem + (1 - p) * 65536;

    // ---- P1: read A[m0..3]x2ks + B[n0,1]x2ks (12); stage Ah0(t+1); Q00
#pragma unroll
    for (int mi = 0; mi < 4; ++mi)
#pragma unroll
      for (int ks = 0; ks < 2; ++ks)
        af[mi][ks] = *(const s16x8*)(As + aoff0 + mi * 2048 + ((ks * 64 + lh * 16) ^ xsw));
#pragma unroll
    for (int ni = 0; ni < 2; ++ni)
#pragma unroll
      for (int ks = 0; ks < 2; ++ks)
        bf[ni][ks] = *(const s16x8*)(Bs + boff0 + ni * 2048 + ((ks * 64 + lh * 16) ^ xsw));
    if (t + 1 < 16) STAGE(AbH[0], (t + 1) * 128, Asn + 0);
    __builtin_amdgcn_s_barrier();
    asm volatile("s_waitcnt lgkmcnt(0)" ::: "memory");
    __builtin_amdgcn_sched_barrier(0);
    __builtin_amdgcn_s_setprio(1);
#pragma unroll
    for (int mi = 0; mi < 4; ++mi)
#pragma unroll
      for (int ni = 0; ni < 2; ++ni)
#pragma unroll
        for (int ks = 0; ks < 2; ++ks)
          acc[mi][ni] = __builtin_amdgcn_mfma_f32_16x16x32_bf16(af[mi][ks], bf[ni][ks], acc[mi][ni], 0, 0, 0);
    __builtin_amdgcn_s_setprio(0);
    __builtin_amdgcn_s_barrier();

    // ---- P2: read B[n2,3] (4); stage Ah1(t+1); Q01
#pragma unroll
    for (int ni = 0; ni < 2; ++ni)
#pragma unroll
      for (int ks = 0; ks < 2; ++ks)
        bf[2 + ni][ks] = *(const s16x8*)(Bs + boff0 + (2 + ni) * 2048 + ((ks * 64 + lh * 16) ^ xsw));
    if (t + 1 < 16) STAGE(AbH[1], (t + 1) * 128, Asn + 16384);
    __builtin_amdgcn_s_barrier();
    asm volatile("s_waitcnt lgkmcnt(0)" ::: "memory");
    __builtin_amdgcn_sched_barrier(0);
    __builtin_amdgcn_s_setprio(1);
#pragma unroll
    for (int mi = 0; mi < 4; ++mi)
#pragma unroll
      for (int ni = 0; ni < 2; ++ni)
#pragma unroll
        for (int ks = 0; ks < 2; ++ks)
          acc[mi][2 + ni] = __builtin_amdgcn_mfma_f32_16x16x32_bf16(af[mi][ks], bf[2 + ni][ks], acc[mi][2 + ni], 0, 0, 0);
    __builtin_amdgcn_s_setprio(0);
    __builtin_amdgcn_s_barrier();   // buf[p].B fully read chip-wide after this

    // ---- P3: read A[m4..7] (8); stage Bh0(t+2) into buf[p]; Q10
#pragma unroll
    for (int mi = 0; mi < 4; ++mi)
#pragma unroll
      for (int ks = 0; ks < 2; ++ks)
        af[mi][ks] = *(const s16x8*)(As + aoff0 + (4 + mi) * 2048 + ((ks * 64 + lh * 16) ^ xsw));
    if (t + 2 < 16) STAGE(BbH[0], (t + 2) * 128, Bs + 0);
    __builtin_amdgcn_s_barrier();
    asm volatile("s_waitcnt lgkmcnt(0)" ::: "memory");
    __builtin_amdgcn_sched_barrier(0);
    __builtin_amdgcn_s_setprio(1);
#pragma unroll
    for (int mi = 0; mi < 4; ++mi)
#pragma unroll
      for (int ni = 0; ni < 2; ++ni)
#pragma unroll
        for (int ks = 0; ks < 2; ++ks)
          acc[4 + mi][ni] = __builtin_amdgcn_mfma_f32_16x16x32_bf16(af[mi][ks], bf[ni][ks], acc[4 + mi][ni], 0, 0, 0);
    __builtin_amdgcn_s_setprio(0);
    __builtin_amdgcn_s_barrier();

    // ---- P4: stage Bh1(t+2); Q11; counted vmcnt; single end barrier
    if (t + 2 < 16) STAGE(BbH[1], (t + 2) * 128, Bs + 16384);
    __builtin_amdgcn_s_setprio(1);
#pragma unroll
    for (int mi = 0; mi < 4; ++mi)
#pragma unroll
      for (int ni = 0; ni < 2; ++ni)
#pragma unroll
        for (int ks = 0; ks < 2; ++ks)
          acc[4 + mi][2 + ni] = __builtin_amdgcn_mfma_f32_16x16x32_bf16(af[mi][ks], bf[2 + ni][ks], acc[4 + mi][2 + ni], 0, 0, 0);
    __builtin_amdgcn_s_setprio(0);
    __builtin_amdgcn_sched_barrier(0);
    if (t < 14) { asm volatile("s_waitcnt vmcnt(4)" ::: "memory"); }
    else        { asm volatile("s_waitcnt vmcnt(0)" ::: "memory"); }
    __builtin_amdgcn_s_barrier();
  }
#undef STAGE

  // epilogue: C/D layout col=lane&15, row=(lane>>4)*4+reg
#pragma unroll
  for (int mi = 0; mi < 8; ++mi) {
    int row0 = brow0 + wm * 128 + mi * 16 + lh * 4;
#pragma unroll
    for (int r = 0; r < 4; ++r) {
      int row = row0 + r;
      float xv = (MODE == 1) ? x2[row] : 0.0f;
#pragma unroll
      for (int ni = 0; ni < 4; ++ni) {
        int col = bcol0 + wn * 64 + ni * 16 + lr;
        float v = acc[mi][ni][r];
        if (MODE == 1) {
          float d2 = xv + c2[col] - 2.0f * v;
          v = -sqrtf(fmaxf(d2, 0.0f));
        }
        out[(size_t)row * NN + col] = v;
      }
    }
  }
}

// ---------------------------------------------------------------------------
extern "C" void kernel_launch(void* const* d_in, const int* in_sizes, int n_in,
                              void* d_out, int out_size, void* d_ws, size_t ws_size,
                              hipStream_t stream) {
  const float* emb   = (const float*)d_in[0];
  const float* cb    = (const float*)d_in[1];
  const float* noise = (const float*)d_in[2];

  float* quant  = (float*)d_out;
  float* logits = (float*)d_out + (size_t)MM * NN;

  char* ws = (char*)d_ws;
  unsigned short* XW = (unsigned short*)ws;               // 64 MiB X/W bf16
  unsigned short* CB = (unsigned short*)(ws + 67108864);  // 2 MiB
  unsigned short* CT = (unsigned short*)(ws + 69206016);  // 2 MiB
  float* x2 = (float*)(ws + 71303168);                    // 128 KiB
  float* c2 = (float*)(ws + 71434240);                    // 4 KiB

  // allow 128 KiB dynamic LDS (idempotent; harmless if already set)
  static bool attr_done = false;
  if (!attr_done) {
    hipFuncSetAttribute((const void*)gemm256<1>,
                        hipFuncAttributeMaxDynamicSharedMemorySize, 131072);
    hipFuncSetAttribute((const void*)gemm256<0>,
                        hipFuncAttributeMaxDynamicSharedMemorySize, 131072);
    attr_done = true;
  }

  prep_cb<<<dim3(1024), dim3(256), 0, stream>>>(cb, CB, CT, c2);
  prep_x<<<dim3(MM), dim3(256), 0, stream>>>(emb, XW, x2);
  gemm256<1><<<dim3(512), dim3(512), 131072, stream>>>(XW, CB, logits, x2, c2);
  softmax_k<<<dim3(MM), dim3(256), 0, stream>>>(logits, noise, XW);
  gemm256<0><<<dim3(512), dim3(512), 131072, stream>>>(XW, CT, quant, nullptr, nullptr);
}